// Round 2
// baseline (151.610 us; speedup 1.0000x reference)
//
#include <hip/hip_runtime.h>
#include <math.h>

// FFF fused forward v2 — full tree speculation (all 21 dots, they are exactly
// the reachable node set under clip(.,0,20)), f32 accum, DPP wave reduction,
// 2 tokens interleaved per wave for LDS-read reuse.

#define D 768
#define NF4 (D / 4)   // 192
#define NN 21
#define TPB 1024      // 16 waves/block
#define NBLK 256      // 1 block/CU (126 KB LDS)
#define NWAVES (NBLK * (TPB / 64))  // 4096

__device__ __forceinline__ float gelu_exact(float v) {
  return 0.5f * v * (1.0f + erff(v * 0.70710678118654752440f));
}

// DPP add: v += lane-permuted(v). VALU pipe, no LDS traffic.
template <int CTRL>
__device__ __forceinline__ float dppadd(float v) {
  int m = __builtin_amdgcn_update_dpp(0, __float_as_int(v), CTRL, 0xF, 0xF, true);
  return v + __int_as_float(m);
}

// Full 64-lane sum. Steps {row_mirror, half_mirror, xor2, xor1} form the
// xor-coset chain {0,7,8,15}->span{2,7,8}->all16 (disjoint at every step),
// then xor16/xor32 via shfl (LDS pipe, only 2 ops).
__device__ __forceinline__ float wave_red(float v) {
  v = dppadd<0x140>(v);  // ROW_MIRROR
  v = dppadd<0x141>(v);  // ROW_HALF_MIRROR
  v = dppadd<0x4E>(v);   // QUAD_PERM [2,3,0,1]  (xor 2)
  v = dppadd<0xB1>(v);   // QUAD_PERM [1,0,3,2]  (xor 1)
  v += __shfl_xor(v, 16);
  v += __shfl_xor(v, 32);
  return v;
}

__device__ __forceinline__ float dot12(float4 a0, float4 a1, float4 a2,
                                       float4 w0, float4 w1, float4 w2) {
  float s = a0.x * w0.x;
  s = fmaf(a0.y, w0.y, s); s = fmaf(a0.z, w0.z, s); s = fmaf(a0.w, w0.w, s);
  s = fmaf(a1.x, w1.x, s); s = fmaf(a1.y, w1.y, s); s = fmaf(a1.z, w1.z, s);
  s = fmaf(a1.w, w1.w, s); s = fmaf(a2.x, w2.x, s); s = fmaf(a2.y, w2.y, s);
  s = fmaf(a2.z, w2.z, s); s = fmaf(a2.w, w2.w, s);
  return s;
}

__device__ __forceinline__ void accrow(const float* __restrict__ row, int lane,
                                       float g, float4& a0, float4& a1,
                                       float4& a2) {
  const float4* r = (const float4*)row;
  float4 w0 = r[lane], w1 = r[lane + 64], w2 = r[lane + 128];
  a0.x = fmaf(g, w0.x, a0.x); a0.y = fmaf(g, w0.y, a0.y);
  a0.z = fmaf(g, w0.z, a0.z); a0.w = fmaf(g, w0.w, a0.w);
  a1.x = fmaf(g, w1.x, a1.x); a1.y = fmaf(g, w1.y, a1.y);
  a1.z = fmaf(g, w1.z, a1.z); a1.w = fmaf(g, w1.w, a1.w);
  a2.x = fmaf(g, w2.x, a2.x); a2.y = fmaf(g, w2.y, a2.y);
  a2.z = fmaf(g, w2.z, a2.z); a2.w = fmaf(g, w2.w, a2.w);
}

// r[21]: wave-uniform node logits (all indices compile-time -> registers).
// Traversal is pure cndmask selects; out = sum of 5 weighted w_out rows.
__device__ __forceinline__ void token_out(const float (&r)[NN],
                                          const float* __restrict__ s_wo,
                                          int lane, float* __restrict__ outp) {
  float l0 = r[0];
  int b0 = l0 > 0.0f;
  float l1 = b0 ? r[2] : r[1];
  int b1 = l1 > 0.0f;
  float l2 = b0 ? (b1 ? r[6] : r[5]) : (b1 ? r[4] : r[3]);
  int b2 = l2 > 0.0f;
  float m0 = b2 ? r[8] : r[7];
  float m1 = b2 ? r[10] : r[9];
  float m2 = b2 ? r[12] : r[11];
  float m3 = b2 ? r[14] : r[13];
  float l3 = b0 ? (b1 ? m3 : m2) : (b1 ? m1 : m0);
  int b3 = l3 > 0.0f;
  int i4 = (b0 << 3) | (b1 << 2) | (b2 << 1) | b3;  // 0..15
  float l4 = r[15];
  l4 = (i4 >= 1) ? r[16] : l4;
  l4 = (i4 >= 2) ? r[17] : l4;
  l4 = (i4 >= 3) ? r[18] : l4;
  l4 = (i4 >= 4) ? r[19] : l4;
  l4 = (i4 >= 5) ? r[20] : l4;

  int u1 = 1 + b0;
  int u2 = 3 + 2 * b0 + b1;
  int u3 = 7 + 4 * b0 + 2 * b1 + b2;
  int u4 = 15 + (i4 < 5 ? i4 : 5);

  float g1 = gelu_exact(l0);
  float g2 = gelu_exact(l1);
  float g3 = gelu_exact(l2);
  float g4 = gelu_exact(l3);
  float g5 = gelu_exact(l4) + 5.0f * gelu_exact(r[20]);

  float4 a0 = {0.f, 0.f, 0.f, 0.f}, a1 = a0, a2 = a0;
  accrow(s_wo + u1 * D, lane, g1, a0, a1, a2);
  accrow(s_wo + u2 * D, lane, g2, a0, a1, a2);
  accrow(s_wo + u3 * D, lane, g3, a0, a1, a2);
  accrow(s_wo + u4 * D, lane, g4, a0, a1, a2);
  accrow(s_wo + (NN - 1) * D, lane, g5, a0, a1, a2);

  float4* op = (float4*)outp;
  op[lane] = a0;
  op[lane + 64] = a1;
  op[lane + 128] = a2;
}

__global__ __launch_bounds__(TPB, 1) void fff_kernel(
    const float* __restrict__ x, const float* __restrict__ wi,
    const float* __restrict__ wo, float* __restrict__ out, int ntok) {
  __shared__ __align__(16) float s_wi[NN * D];  // 63 KB
  __shared__ __align__(16) float s_wo[NN * D];  // 63 KB

  const int tid = threadIdx.x;
  {
    const float4* a = (const float4*)wi;
    const float4* b = (const float4*)wo;
    float4* sa = (float4*)s_wi;
    float4* sb = (float4*)s_wo;
    for (int i = tid; i < NN * NF4; i += TPB) {
      sa[i] = a[i];
      sb[i] = b[i];
    }
  }
  __syncthreads();

  const int lane = tid & 63;
  const int wid = (blockIdx.x << 4) | (tid >> 6);
  const float4* swi4 = (const float4*)s_wi;

  for (int tA = wid; tA < ntok; tA += 2 * NWAVES) {
    const int tB = tA + NWAVES;
    const bool hasB = tB < ntok;
    const float4* xa = (const float4*)(x + (size_t)tA * D);
    float4 xa0 = xa[lane], xa1 = xa[lane + 64], xa2 = xa[lane + 128];
    const float4* xb = (const float4*)(x + (size_t)(hasB ? tB : tA) * D);
    float4 xb0 = xb[lane], xb1 = xb[lane + 64], xb2 = xb[lane + 128];

    float rA[NN], rB[NN];
#pragma unroll
    for (int n = 0; n < NN; ++n) {
      float4 w0 = swi4[n * NF4 + lane];
      float4 w1 = swi4[n * NF4 + lane + 64];
      float4 w2 = swi4[n * NF4 + lane + 128];
      rA[n] = dot12(xa0, xa1, xa2, w0, w1, w2);
      rB[n] = dot12(xb0, xb1, xb2, w0, w1, w2);
    }
#pragma unroll
    for (int n = 0; n < NN; ++n) {
      rA[n] = wave_red(rA[n]);
      rB[n] = wave_red(rB[n]);
    }

    token_out(rA, s_wo, lane, out + (size_t)tA * D);
    if (hasB) token_out(rB, s_wo, lane, out + (size_t)tB * D);
  }
}

extern "C" void kernel_launch(void* const* d_in, const int* in_sizes, int n_in,
                              void* d_out, int out_size, void* d_ws,
                              size_t ws_size, hipStream_t stream) {
  const float* x = (const float*)d_in[0];
  const float* wi = (const float*)d_in[1];
  const float* wo = (const float*)d_in[2];
  float* out = (float*)d_out;
  const int ntok = in_sizes[0] / D;  // 16384
  fff_kernel<<<NBLK, TPB, 0, stream>>>(x, wi, wo, out, ntok);
}